// Round 6
// baseline (1358.454 us; speedup 1.0000x reference)
//
#include <hip/hip_runtime.h>
#include <math.h>

// Sinkhorn EMD loss, B=32, N=1024, 3-D points, EPS=0.02, 50 iters.
// R5: 8-row register tiling per wave (each ds_read_b128 feeds 8 rows,
// halves per-element LDS/loop overhead vs R1's 4), grid 1024 WGs (halves
// staging duplication), single-pass staging with S folded at first write.

#define BATCH 32
#define NPT 1024
#define EPS 0.02f
#define ITERS 50
#define RPW 8                  // rows per wave
#define ROWS_PER_WG 32         // 4 waves/WG * RPW

static __device__ __forceinline__ float wave_max(float v) {
    #pragma unroll
    for (int off = 32; off > 0; off >>= 1)
        v = fmaxf(v, __shfl_xor(v, off, 64));
    return v;
}
static __device__ __forceinline__ float wave_sum(float v) {
    #pragma unroll
    for (int off = 32; off > 0; off >>= 1)
        v += __shfl_xor(v, off, 64);
    return v;
}

// out_pot[b][i] = EPS*(log_marg - logsumexp_j((col_pot[b][j] - C(b,i,j))/EPS))
// C = sqrt(|row_pts_i - col_pts_j|^2 + 1e-12).
// 4 waves/WG, each wave owns 8 rows processed SIMULTANEOUSLY over the k-loop.
__global__ __launch_bounds__(256) void sinkhorn_half(
    const float* __restrict__ row_pts,   // [B][N][3]
    const float* __restrict__ col_pts,   // [B][N][3]
    const float* __restrict__ col_pot,   // [B][N]
    float* __restrict__ out_pot)         // [B][N]
{
    constexpr float LOG2E = 1.4426950408889634f;
    constexpr float LN2   = 0.6931471805599453f;
    constexpr float K2    = LOG2E / EPS;             // exp2-domain scale
    constexpr float LOGMARG = -6.93147180559945309f; // ln(1/1024)

    __shared__ float4 cols[NPT];   // {x, y, z, pot*K2 - S}  16 KB
    __shared__ float  wmax[4];

    const int wg_per_batch = NPT / ROWS_PER_WG;  // 32
    const int b  = blockIdx.x / wg_per_batch;
    const int wg = blockIdx.x % wg_per_batch;
    const int tid = threadIdx.x;
    const int wave = tid >> 6;
    const int lane = tid & 63;

    const float* cp = col_pts + (size_t)b * NPT * 3;
    const float* pp = col_pot + (size_t)b * NPT;

    // Stage: pot*K2 into registers first, block-max, then ONE LDS write
    // with the shift S already folded (saves the R1 read-modify-write pass).
    float w[4];
    float lmax = -3.4e38f;
    #pragma unroll
    for (int r = 0; r < 4; ++r) {
        int j = tid + 256 * r;
        w[r] = pp[j] * K2;
        lmax = fmaxf(lmax, w[r]);
    }
    lmax = wave_max(lmax);
    if (lane == 0) wmax[wave] = lmax;
    __syncthreads();
    // Shift S: terms exp2(pot*K2 - C*K2 - S) <= 2^60 (no overflow) and the
    // argmax-j term >= 2^(60 - sqrt(3)*K2) = 2^-64.9 (no fatal underflow).
    const float S = fmaxf(fmaxf(wmax[0], wmax[1]), fmaxf(wmax[2], wmax[3])) - 60.0f;
    #pragma unroll
    for (int r = 0; r < 4; ++r) {
        int j = tid + 256 * r;
        cols[j] = make_float4(cp[3*j], cp[3*j+1], cp[3*j+2], w[r] - S);
    }
    __syncthreads();

    const float* rp = row_pts + (size_t)b * NPT * 3;
    float* op = out_pot + (size_t)b * NPT;

    const int i0 = wg * ROWS_PER_WG + wave * RPW;
    float tx[RPW], ty[RPW], tz[RPW], s[RPW];
    #pragma unroll
    for (int r = 0; r < RPW; ++r) {
        tx[r] = rp[3*(i0+r)]; ty[r] = rp[3*(i0+r)+1]; tz[r] = rp[3*(i0+r)+2];
        s[r] = 0.f;
    }

    #pragma unroll 4
    for (int k = 0; k < 16; ++k) {
        float4 c = cols[lane + 64 * k];
        #pragma unroll
        for (int r = 0; r < RPW; ++r) {
            float dx = tx[r] - c.x, dy = ty[r] - c.y, dz = tz[r] - c.z;
            float d2 = fmaf(dx, dx, fmaf(dy, dy, fmaf(dz, dz, 1e-12f)));
            float C  = __builtin_amdgcn_sqrtf(d2);
            float arg = fmaf(C, -K2, c.w);
            s[r] += __builtin_amdgcn_exp2f(arg);
        }
    }
    #pragma unroll
    for (int r = 0; r < RPW; ++r) s[r] = wave_sum(s[r]);
    if (lane == 0) {
        #pragma unroll
        for (int r = 0; r < RPW; ++r) {
            float lse = (S + __builtin_amdgcn_logf(s[r])) * LN2;  // natural-log LSE
            op[i0 + r] = EPS * (LOGMARG - lse);
        }
    }
}

// acc += sum_ij C_ij * exp((f_i + g_j - C_ij)/EPS)
__global__ __launch_bounds__(256) void emd_final(
    const float* __restrict__ t_pts,   // [B][N][3]
    const float* __restrict__ s_pts,   // [B][N][3]
    const float* __restrict__ f,       // [B][N]
    const float* __restrict__ g,       // [B][N]
    float* __restrict__ acc)
{
    constexpr float LOG2E = 1.4426950408889634f;
    constexpr float K2    = LOG2E / EPS;

    __shared__ float4 cols[NPT];   // {x, y, z, g*K2 - S}
    __shared__ float  wmax[4];
    __shared__ float  accsm[4];

    const int wg_per_batch = NPT / ROWS_PER_WG;  // 32
    const int b  = blockIdx.x / wg_per_batch;
    const int wg = blockIdx.x % wg_per_batch;
    const int tid = threadIdx.x;
    const int wave = tid >> 6;
    const int lane = tid & 63;

    const float* cp = s_pts + (size_t)b * NPT * 3;
    const float* gp = g + (size_t)b * NPT;

    float w[4];
    float lmax = -3.4e38f;
    #pragma unroll
    for (int r = 0; r < 4; ++r) {
        int j = tid + 256 * r;
        w[r] = gp[j] * K2;
        lmax = fmaxf(lmax, w[r]);
    }
    lmax = wave_max(lmax);
    if (lane == 0) wmax[wave] = lmax;
    __syncthreads();
    const float S = fmaxf(fmaxf(wmax[0], wmax[1]), fmaxf(wmax[2], wmax[3])) - 60.0f;
    #pragma unroll
    for (int r = 0; r < 4; ++r) {
        int j = tid + 256 * r;
        cols[j] = make_float4(cp[3*j], cp[3*j+1], cp[3*j+2], w[r] - S);
    }
    __syncthreads();

    const float* rp = t_pts + (size_t)b * NPT * 3;
    const float* fp = f + (size_t)b * NPT;

    const int i0 = wg * ROWS_PER_WG + wave * RPW;
    float tx[RPW], ty[RPW], tz[RPW], loc[RPW];
    #pragma unroll
    for (int r = 0; r < RPW; ++r) {
        tx[r] = rp[3*(i0+r)]; ty[r] = rp[3*(i0+r)+1]; tz[r] = rp[3*(i0+r)+2];
        loc[r] = 0.f;
    }

    #pragma unroll 4
    for (int k = 0; k < 16; ++k) {
        float4 c = cols[lane + 64 * k];
        #pragma unroll
        for (int r = 0; r < RPW; ++r) {
            float dx = tx[r] - c.x, dy = ty[r] - c.y, dz = tz[r] - c.z;
            float d2 = fmaf(dx, dx, fmaf(dy, dy, fmaf(dz, dz, 1e-12f)));
            float C  = __builtin_amdgcn_sqrtf(d2);
            float p  = __builtin_amdgcn_exp2f(fmaf(C, -K2, c.w));
            loc[r] = fmaf(p, C, loc[r]);   // sum_j C * 2^(g K2 - S - C K2)
        }
    }
    // per-row scale 2^(f_i K2 + S), summed within the wave
    float wtot = 0.f;
    #pragma unroll
    for (int r = 0; r < RPW; ++r) {
        float sc = __builtin_amdgcn_exp2f(fmaf(fp[i0 + r], K2, S));
        wtot = fmaf(sc, loc[r], wtot);
    }
    wtot = wave_sum(wtot);
    if (lane == 0) accsm[wave] = wtot;
    __syncthreads();
    if (tid == 0) {
        float t = accsm[0] + accsm[1] + accsm[2] + accsm[3];
        atomicAdd(acc, t);
    }
}

__global__ void finalize_kernel(const float* __restrict__ acc,
                                float* __restrict__ out)
{
    out[0] = acc[0] * (1.0f / ((float)BATCH * (float)NPT));
}

extern "C" void kernel_launch(void* const* d_in, const int* in_sizes, int n_in,
                              void* d_out, int out_size, void* d_ws, size_t ws_size,
                              hipStream_t stream) {
    const float* tmpl = (const float*)d_in[0];   // [32,1024,3]
    const float* src  = (const float*)d_in[1];   // [32,1024,3]
    float* out = (float*)d_out;

    float* f   = (float*)d_ws;               // [B*N]
    float* g   = f + BATCH * NPT;            // [B*N]
    float* acc = g + BATCH * NPT;            // [1]

    hipMemsetAsync(g, 0, BATCH * NPT * sizeof(float), stream);
    hipMemsetAsync(acc, 0, sizeof(float), stream);

    dim3 grid(BATCH * (NPT / ROWS_PER_WG));  // 1024 WGs
    dim3 block(256);

    for (int it = 0; it < ITERS; ++it) {
        sinkhorn_half<<<grid, block, 0, stream>>>(tmpl, src, g, f);
        sinkhorn_half<<<grid, block, 0, stream>>>(src, tmpl, f, g);
    }
    emd_final<<<grid, block, 0, stream>>>(tmpl, src, f, g, acc);
    finalize_kernel<<<1, 1, 0, stream>>>(acc, out);
}